// Round 7
// baseline (416.579 us; speedup 1.0000x reference)
//
#include <hip/hip_runtime.h>
#include <hip/hip_bf16.h>
#include <cmath>
#include <cstdint>

#define T 2048
#define H 1024
#define NH 16
#define NKV 4
#define DH 64
#define NE 8
#define FF 1024
#define QKVN ((NH + 2 * NKV) * DH) /* 1536 */
#define EPS 1e-5f
#define ATTN_SCALE 0.125f
#define LOG2E 1.44269504f
#define MBOUND 12.0f  /* > 64*0.125*log2e = 11.54; scores can't exceed it (rms-normed q,k) */

typedef short bf16x8 __attribute__((ext_vector_type(8)));
typedef float floatx4 __attribute__((ext_vector_type(4)));

__device__ __forceinline__ void gload16(const void* g, void* l) {
  __builtin_amdgcn_global_load_lds((const __attribute__((address_space(1))) void*)g,
                                   (__attribute__((address_space(3))) void*)l, 16, 0, 0);
}

// ---------------- rmsnorm rows of 1024 -> bf16 ----------------
__global__ __launch_bounds__(256) void rmsnorm1024(const float* __restrict__ x,
                                                   const float* __restrict__ w,
                                                   __hip_bfloat16* __restrict__ yb) {
  int row = blockIdx.x;
  const float4* x4 = (const float4*)(x + (size_t)row * H);
  float4 v = x4[threadIdx.x];
  float s = v.x * v.x + v.y * v.y + v.z * v.z + v.w * v.w;
  #pragma unroll
  for (int o = 32; o; o >>= 1) s += __shfl_down(s, o, 64);
  __shared__ float red[4];
  if ((threadIdx.x & 63) == 0) red[threadIdx.x >> 6] = s;
  __syncthreads();
  s = red[0] + red[1] + red[2] + red[3];
  float inv = rsqrtf(s * (1.0f / (float)H) + EPS);
  float4 wv = ((const float4*)w)[threadIdx.x];
  __hip_bfloat16* yp = yb + (size_t)row * H + threadIdx.x * 4;
  yp[0] = __float2bfloat16(v.x * inv * wv.x);
  yp[1] = __float2bfloat16(v.y * inv * wv.y);
  yp[2] = __float2bfloat16(v.z * inv * wv.z);
  yp[3] = __float2bfloat16(v.w * inv * wv.w);
}

// -------- fused: resid = a+b; h2 = rmsnorm(resid)*w (fp32 + bf16) --------
__global__ __launch_bounds__(256) void fused_add_rms(const float* __restrict__ a,
                                                     const float* __restrict__ b,
                                                     float* __restrict__ resid,
                                                     const float* __restrict__ w,
                                                     float* __restrict__ yf,
                                                     __hip_bfloat16* __restrict__ yb) {
  int row = blockIdx.x;
  float4 av = ((const float4*)(a + (size_t)row * H))[threadIdx.x];
  float4 bv = ((const float4*)(b + (size_t)row * H))[threadIdx.x];
  float4 v = make_float4(av.x + bv.x, av.y + bv.y, av.z + bv.z, av.w + bv.w);
  ((float4*)(resid + (size_t)row * H))[threadIdx.x] = v;
  float s = v.x * v.x + v.y * v.y + v.z * v.z + v.w * v.w;
  #pragma unroll
  for (int o = 32; o; o >>= 1) s += __shfl_down(s, o, 64);
  __shared__ float red[4];
  if ((threadIdx.x & 63) == 0) red[threadIdx.x >> 6] = s;
  __syncthreads();
  s = red[0] + red[1] + red[2] + red[3];
  float inv = rsqrtf(s * (1.0f / (float)H) + EPS);
  float4 wv = ((const float4*)w)[threadIdx.x];
  float o0 = v.x * inv * wv.x, o1 = v.y * inv * wv.y, o2 = v.z * inv * wv.z, o3 = v.w * inv * wv.w;
  ((float4*)(yf + (size_t)row * H))[threadIdx.x] = make_float4(o0, o1, o2, o3);
  __hip_bfloat16* yp = yb + (size_t)row * H + threadIdx.x * 4;
  yp[0] = __float2bfloat16(o0);
  yp[1] = __float2bfloat16(o1);
  yp[2] = __float2bfloat16(o2);
  yp[3] = __float2bfloat16(o3);
}

// ------- fp32 [R][C] -> bf16 [C][R]; z batched, last z optionally from srcS -------
__global__ __launch_bounds__(256) void tcast9(const float* __restrict__ srcE,
                                              const float* __restrict__ srcS,
                                              __hip_bfloat16* __restrict__ dst, int R, int C,
                                              long long srcStride, long long dstStride,
                                              long long sBatch, long long dBatch) {
  int z = blockIdx.z;
  const float* src = (srcS && z == (int)gridDim.z - 1) ? srcS : srcE + (long long)z * sBatch;
  dst += (long long)z * dBatch;
  int c0 = blockIdx.x * 64, r0 = blockIdx.y * 32;
  __shared__ float tile[32][65];
  int tid = threadIdx.x;
  int lr = tid >> 4;
  int lc = (tid & 15) * 4;
  #pragma unroll
  for (int it = 0; it < 2; it++) {
    float4 v = *(const float4*)(src + (long long)(r0 + lr + it * 16) * srcStride + c0 + lc);
    tile[lr + it * 16][lc + 0] = v.x;
    tile[lr + it * 16][lc + 1] = v.y;
    tile[lr + it * 16][lc + 2] = v.z;
    tile[lr + it * 16][lc + 3] = v.w;
  }
  __syncthreads();
  int oc = tid >> 2;
  int rr = (tid & 3) * 8;
  short ov[8];
  #pragma unroll
  for (int i = 0; i < 8; i++) {
    __hip_bfloat16 b = __float2bfloat16(tile[rr + i][oc]);
    ov[i] = *(short*)&b;
  }
  *(bf16x8*)((short*)dst + (long long)(c0 + oc) * dstStride + r0 + rr) = *(bf16x8*)ov;
}

// ---- bf16 MFMA GEMM, 128x64 tile, BK=64, XOR-swizzled LDS, double-buffered ----
// C[M,N] = A[M,K] * Bt[N,K]^T ; last z slot (if A2) uses A2/full rows/Cout2.
// out_mode: 0 = fp32 store, 1 = bf16 store, 2 = fp32 atomicAdd (expert rows via permmap)
__global__ __launch_bounds__(256) void gemm_bf16(const __hip_bfloat16* __restrict__ A,
                                                 const __hip_bfloat16* __restrict__ A2,
                                                 const __hip_bfloat16* __restrict__ Bt,
                                                 void* __restrict__ Cout, void* __restrict__ Cout2,
                                                 int M, int N, int K, int out_mode,
                                                 const int* __restrict__ row_offs,
                                                 long long strideB,
                                                 const int* __restrict__ permmap) {
  int e = blockIdx.z;
  bool sh = (A2 != nullptr && e == (int)gridDim.z - 1);
  int rbeg = 0, rend = M;
  const __hip_bfloat16* Ap = A;
  void* Cp = Cout;
  if (sh) {
    Ap = A2; Cp = Cout2;
  } else if (row_offs) {
    rbeg = row_offs[e]; rend = row_offs[e + 1];
  }
  long long m0 = rbeg + (long long)blockIdx.y * 128;
  if (m0 >= rend) return;
  long long n0 = (long long)blockIdx.x * 64;
  const __hip_bfloat16* Bp = Bt + (long long)e * strideB;

  __shared__ unsigned short As[2 * 128 * 64];
  __shared__ unsigned short Bs[2 * 64 * 64];

  int tid = threadIdx.x;
  int lane = tid & 63, w = tid >> 6;
  int wr = (w >> 1) * 64, wc = (w & 1) * 32;
  int qd = lane >> 4, ln16 = lane & 15;
  int l7 = ln16 & 7;

  floatx4 acc[4][2];
  floatx4 zero = {0.f, 0.f, 0.f, 0.f};
  #pragma unroll
  for (int i = 0; i < 4; i++)
    #pragma unroll
    for (int j = 0; j < 2; j++) acc[i][j] = zero;

  int rowA[4], kcA[4];
  long long raClamp[4];
  #pragma unroll
  for (int it = 0; it < 4; it++) {
    int chunk = tid + it * 256;
    rowA[it] = chunk >> 3;
    kcA[it] = ((chunk & 7) ^ (rowA[it] & 7)) * 8;
    long long ra = m0 + rowA[it];
    raClamp[it] = (ra >= rend) ? (rend - 1) : ra;
  }

  int niter = K >> 6;
  // prologue: tile 0 -> buffer 0
  #pragma unroll
  for (int it = 0; it < 4; it++)
    gload16(Ap + raClamp[it] * K + kcA[it], As + (tid + it * 256) * 8);
  #pragma unroll
  for (int it = 0; it < 2; it++)
    gload16(Bp + (n0 + rowA[it]) * K + kcA[it], Bs + (tid + it * 256) * 8);
  __syncthreads();

  for (int k = 0; k < niter; k++) {
    int cur = k & 1;
    if (k + 1 < niter) {
      int nxt = cur ^ 1;
      int k0 = (k + 1) << 6;
      #pragma unroll
      for (int it = 0; it < 4; it++)
        gload16(Ap + raClamp[it] * K + k0 + kcA[it], As + nxt * 8192 + (tid + it * 256) * 8);
      #pragma unroll
      for (int it = 0; it < 2; it++)
        gload16(Bp + (n0 + rowA[it]) * K + k0 + kcA[it], Bs + nxt * 4096 + (tid + it * 256) * 8);
    }
    const unsigned short* Asc = As + cur * 8192;
    const unsigned short* Bsc = Bs + cur * 4096;
    #pragma unroll
    for (int s = 0; s < 2; s++) {
      bf16x8 af[4], bfr[2];
      #pragma unroll
      for (int i = 0; i < 4; i++) {
        int row = wr + i * 16 + ln16;
        af[i] = *(const bf16x8*)(Asc + row * 64 + (((s * 4 + qd) ^ l7) * 8));
      }
      #pragma unroll
      for (int j = 0; j < 2; j++) {
        int row = wc + j * 16 + ln16;
        bfr[j] = *(const bf16x8*)(Bsc + row * 64 + (((s * 4 + qd) ^ l7) * 8));
      }
      #pragma unroll
      for (int i = 0; i < 4; i++)
        #pragma unroll
        for (int j = 0; j < 2; j++)
          acc[i][j] = __builtin_amdgcn_mfma_f32_16x16x32_bf16(af[i], bfr[j], acc[i][j], 0, 0, 0);
    }
    __syncthreads();
  }

  #pragma unroll
  for (int i = 0; i < 4; i++) {
    #pragma unroll
    for (int r = 0; r < 4; r++) {
      long long gm = m0 + wr + i * 16 + qd * 4 + r;
      if (gm < rend) {
        long long gmo = (out_mode == 2 && !sh && permmap) ? permmap[gm] : gm;
        #pragma unroll
        for (int j = 0; j < 2; j++) {
          long long gn = n0 + wc + j * 16 + ln16;
          float v = acc[i][j][r];
          if (out_mode == 1)
            ((__hip_bfloat16*)Cp)[gm * N + gn] = __float2bfloat16(v);
          else if (out_mode == 2)
            atomicAdd(&((float*)Cp)[gmo * N + gn], v);
          else
            ((float*)Cp)[gm * N + gn] = v;
        }
      }
    }
  }
}

// -------- RoPE + per-head rmsnorm; Qb scaled by SCALE*log2e, Kb plain --------
__global__ __launch_bounds__(256) void rope_pack(const float* __restrict__ qkv,
                                                 const int* __restrict__ positions,
                                                 __hip_bfloat16* __restrict__ Qb,
                                                 __hip_bfloat16* __restrict__ Kb) {
  int b = blockIdx.x * 4 + (threadIdx.x >> 6);
  int t = b / (NH + NKV);
  int hh = b % (NH + NKV);
  const float* ptr = qkv + (long long)t * QKVN + hh * DH;
  int d = threadIdx.x & 63;
  float v = ptr[d];
  int fi = d & 31;
  float inv_freq = exp2f(-(float)fi * (18.93156857f / 32.0f));
  float ang = (float)positions[t] * inv_freq;
  float c = __cosf(ang), s = __sinf(ang);
  float other = __shfl_xor(v, 32, 64);
  float r = (d < 32) ? (v * c - other * s) : (v * c + other * s);
  float sq = r * r;
  #pragma unroll
  for (int off = 32; off; off >>= 1) sq += __shfl_xor(sq, off, 64);
  float o = r * rsqrtf(sq * (1.0f / (float)DH) + EPS);
  if (hh < NH)
    Qb[(size_t)t * (NH * DH) + hh * DH + d] = __float2bfloat16(o * (ATTN_SCALE * LOG2E));
  else
    Kb[(size_t)t * (NKV * DH) + (hh - NH) * DH + d] = __float2bfloat16(o);
}

// ---- MFMA flash attention: static-max softmax, double-buffered KV staging ----
__global__ __launch_bounds__(256) void attn_mfma(const __hip_bfloat16* __restrict__ Qb,
                                                 const __hip_bfloat16* __restrict__ Kb,
                                                 const __hip_bfloat16* __restrict__ VtG,
                                                 __hip_bfloat16* __restrict__ ao) {
  int h = blockIdx.y;
  int kvh = h >> 2;
  int nb = gridDim.x;
  int bx = blockIdx.x;
  int qi = (bx & 1) ? (nb - 1 - (bx >> 1)) : (bx >> 1);
  int q0 = qi * 64;

  __shared__ unsigned short Ks[2 * 64 * 64];
  __shared__ unsigned short Vs[2 * 64 * 64];
  __shared__ unsigned short Ps[4 * 16 * 64];

  int tid = threadIdx.x;
  int lane = tid & 63, w = tid >> 6;
  int qd = lane >> 4, ln16 = lane & 15;
  int l7 = ln16 & 7;
  unsigned short* Pw = Ps + w * 16 * 64;

  int r0 = tid >> 3;
  int sc = ((tid & 7) ^ (r0 & 7)) * 8;

  int tq = q0 + w * 16 + ln16;
  const unsigned short* qp = (const unsigned short*)Qb + (size_t)tq * (NH * DH) + h * DH;
  bf16x8 aq[2];
  aq[0] = *(const bf16x8*)(qp + qd * 8);
  aq[1] = *(const bf16x8*)(qp + 32 + qd * 8);

  bf16x8 ones;
  #pragma unroll
  for (int i = 0; i < 8; i++) ones[i] = (short)0x3F80;  // bf16 1.0

  floatx4 O_[4], accl;
  floatx4 zero = {0.f, 0.f, 0.f, 0.f};
  #pragma unroll
  for (int j = 0; j < 4; j++) O_[j] = zero;
  accl = zero;
  int tq_base = q0 + w * 16 + qd * 4;
  int wave_min_row = q0 + w * 16;

  const unsigned short* KbU = (const unsigned short*)Kb;
  const unsigned short* VtU = (const unsigned short*)VtG;

  // prologue: kb=0 tile -> buffer 0
  gload16(KbU + (size_t)(r0) * (NKV * DH) + kvh * DH + sc, Ks + tid * 8);
  gload16(KbU + (size_t)(r0 + 32) * (NKV * DH) + kvh * DH + sc, Ks + tid * 8 + 2048);
  gload16(VtU + (size_t)(kvh * DH + r0) * T + sc, Vs + tid * 8);
  gload16(VtU + (size_t)(kvh * DH + r0 + 32) * T + sc, Vs + tid * 8 + 2048);
  __syncthreads();

  for (int kb = 0; kb < q0 + 64; kb += 64) {
    int cur = (kb >> 6) & 1;
    if (kb < q0) {
      int nxt = cur ^ 1;
      int kn = kb + 64;
      gload16(KbU + (size_t)(kn + r0) * (NKV * DH) + kvh * DH + sc, Ks + nxt * 4096 + tid * 8);
      gload16(KbU + (size_t)(kn + r0 + 32) * (NKV * DH) + kvh * DH + sc, Ks + nxt * 4096 + tid * 8 + 2048);
      gload16(VtU + (size_t)(kvh * DH + r0) * T + kn + sc, Vs + nxt * 4096 + tid * 8);
      gload16(VtU + (size_t)(kvh * DH + r0 + 32) * T + kn + sc, Vs + nxt * 4096 + tid * 8 + 2048);
    }
    const unsigned short* Ksc = Ks + cur * 4096;
    const unsigned short* Vsc = Vs + cur * 4096;

    floatx4 S_[4];
    #pragma unroll
    for (int j = 0; j < 4; j++) S_[j] = zero;
    #pragma unroll
    for (int s = 0; s < 2; s++) {
      bf16x8 bk[4];
      #pragma unroll
      for (int j = 0; j < 4; j++)
        bk[j] = *(const bf16x8*)(Ksc + (j * 16 + ln16) * 64 + (((s * 4 + qd) ^ l7) * 8));
      #pragma unroll
      for (int j = 0; j < 4; j++)
        S_[j] = __builtin_amdgcn_mfma_f32_16x16x32_bf16(aq[s], bk[j], S_[j], 0, 0, 0);
    }

    // p = exp2(s - MBOUND); masked -> 0 (diagonal tile only)
    if (kb + 63 > wave_min_row) {
      #pragma unroll
      for (int j = 0; j < 4; j++) {
        int tk = kb + j * 16 + ln16;
        #pragma unroll
        for (int r = 0; r < 4; r++)
          S_[j][r] = (tk <= tq_base + r) ? exp2f(S_[j][r] - MBOUND) : 0.f;
      }
    } else {
      #pragma unroll
      for (int j = 0; j < 4; j++)
        #pragma unroll
        for (int r = 0; r < 4; r++) S_[j][r] = exp2f(S_[j][r] - MBOUND);
    }

    // P -> per-wave LDS (bf16, XOR swizzle)
    #pragma unroll
    for (int j = 0; j < 4; j++)
      #pragma unroll
      for (int r = 0; r < 4; r++) {
        int row = qd * 4 + r;
        int pc = (((j * 2 + (ln16 >> 3)) ^ (row & 7)) * 8) + l7;
        __hip_bfloat16 pb = __float2bfloat16(S_[j][r]);
        Pw[row * 64 + pc] = *(unsigned short*)&pb;
      }

    // O += P V ; l += P . ones
    #pragma unroll
    for (int s = 0; s < 2; s++) {
      bf16x8 ap = *(const bf16x8*)(Pw + ln16 * 64 + (((s * 4 + qd) ^ l7) * 8));
      bf16x8 bv[4];
      #pragma unroll
      for (int j = 0; j < 4; j++)
        bv[j] = *(const bf16x8*)(Vsc + (j * 16 + ln16) * 64 + (((s * 4 + qd) ^ l7) * 8));
      #pragma unroll
      for (int j = 0; j < 4; j++)
        O_[j] = __builtin_amdgcn_mfma_f32_16x16x32_bf16(ap, bv[j], O_[j], 0, 0, 0);
      accl = __builtin_amdgcn_mfma_f32_16x16x32_bf16(ap, ones, accl, 0, 0, 0);
    }
    __syncthreads();
  }

  float inv[4];
  #pragma unroll
  for (int r = 0; r < 4; r++) inv[r] = 1.0f / accl[r];
  #pragma unroll
  for (int j = 0; j < 4; j++)
    #pragma unroll
    for (int r = 0; r < 4; r++)
      ao[(size_t)(tq_base + r) * (NH * DH) + h * DH + j * 16 + ln16] =
          __float2bfloat16(O_[j][r] * inv[r]);
}

// ------- fused silu-mul over expert (gA2->gP) and shared (gS2->gPs) -------
__global__ void silumul_both(const __hip_bfloat16* __restrict__ gA2,
                             const __hip_bfloat16* __restrict__ gS2,
                             __hip_bfloat16* __restrict__ gP,
                             __hip_bfloat16* __restrict__ gPs, int n4each) {
  int i = blockIdx.x * blockDim.x + threadIdx.x;
  const __hip_bfloat16* src = gA2;
  __hip_bfloat16* dst = gP;
  if (i >= n4each) {
    i -= n4each;
    src = gS2;
    dst = gPs;
  }
  int el = i * 4;
  int row = el >> 10;
  int c = el & (FF - 1);
  const __hip_bfloat16* g = src + (size_t)row * (2 * FF) + c;
  #pragma unroll
  for (int k = 0; k < 4; k++) {
    float av = __bfloat162float(g[k]);
    float bv = __bfloat162float(g[FF + k]);
    dst[el + k] = __float2bfloat16(av / (1.f + __expf(-av)) * bv);
  }
}

// ---------------- router (top-1 + sigmoid gate), fp32 ----------------
__global__ __launch_bounds__(64) void router_kernel(const float* __restrict__ h2,
                                                    const float* __restrict__ rw,
                                                    int* __restrict__ idx,
                                                    float* __restrict__ gate,
                                                    int* __restrict__ counts) {
  int t = blockIdx.x;
  int lane = threadIdx.x;
  float acc[NE] = {};
  for (int k = lane; k < H; k += 64) {
    float hv = h2[(long long)t * H + k];
    float4 r0 = *(const float4*)(rw + (long long)k * NE);
    float4 r1 = *(const float4*)(rw + (long long)k * NE + 4);
    acc[0] += hv * r0.x; acc[1] += hv * r0.y; acc[2] += hv * r0.z; acc[3] += hv * r0.w;
    acc[4] += hv * r1.x; acc[5] += hv * r1.y; acc[6] += hv * r1.z; acc[7] += hv * r1.w;
  }
  #pragma unroll
  for (int off = 32; off; off >>= 1)
    #pragma unroll
    for (int e2 = 0; e2 < NE; e2++) acc[e2] += __shfl_down(acc[e2], off, 64);
  if (lane == 0) {
    int best = 0;
    float bv = acc[0];
    #pragma unroll
    for (int e2 = 1; e2 < NE; e2++)
      if (acc[e2] > bv) { bv = acc[e2]; best = e2; }
    idx[t] = best;
    gate[t] = 1.f / (1.f + expf(-bv));
    atomicAdd(&counts[best], 1);
  }
}

__global__ void zero_counts_kernel(int* c) {
  if (threadIdx.x < 2 * NE) c[threadIdx.x] = 0;
}

__global__ void scan_kernel(const int* __restrict__ counts, int* __restrict__ offs) {
  if (threadIdx.x == 0) {
    int s = 0;
    for (int e2 = 0; e2 < NE; e2++) { offs[e2] = s; s += counts[e2]; }
    offs[NE] = s;
  }
}

// -------- fused: assign permuted slot + gather gated row to xg --------
__global__ __launch_bounds__(256) void assign_gather(const int* __restrict__ idx,
                                                     const int* __restrict__ offs,
                                                     int* __restrict__ cnt2,
                                                     int* __restrict__ perm,
                                                     const float* __restrict__ h2,
                                                     const float* __restrict__ gate,
                                                     __hip_bfloat16* __restrict__ xg) {
  int t = blockIdx.x;
  __shared__ int ps;
  if (threadIdx.x == 0) {
    int e2 = idx[t];
    int p = offs[e2] + atomicAdd(&cnt2[e2], 1);
    perm[p] = t;
    ps = p;
  }
  __syncthreads();
  int p = ps;
  float g = gate[t];
  float4 v = ((const float4*)(h2 + (long long)t * H))[threadIdx.x];
  __hip_bfloat16* yp = xg + (long long)p * H + threadIdx.x * 4;
  yp[0] = __float2bfloat16(v.x * g);
  yp[1] = __float2bfloat16(v.y * g);
  yp[2] = __float2bfloat16(v.z * g);
  yp[3] = __float2bfloat16(v.w * g);
}

// ---------------- launcher ----------------
extern "C" void kernel_launch(void* const* d_in, const int* in_sizes, int n_in,
                              void* d_out, int out_size, void* d_ws, size_t ws_size,
                              hipStream_t stream) {
  const int* positions = (const int*)d_in[0];
  const float* hidden = (const float*)d_in[1];
  const float* ln1_w = (const float*)d_in[2];
  const float* ln2_w = (const float*)d_in[3];
  const float* wqkv = (const float*)d_in[4];
  const float* wo = (const float*)d_in[5];
  const float* router_w = (const float*)d_in[6];
  const float* w_gate = (const float*)d_in[7];
  const float* w_up = (const float*)d_in[8];
  const float* w_down = (const float*)d_in[9];
  const float* sh_gate = (const float*)d_in[10];
  const float* sh_up = (const float*)d_in[11];
  const float* sh_down = (const float*)d_in[12];

  float* out = (float*)d_out;
  float* resid = out + (size_t)T * H;

  char* p = (char*)d_ws;
  auto alloc = [&](size_t bytes) { char* r = p; p += (bytes + 255) & ~(size_t)255; return r; };

  float* qkv = (float*)alloc((size_t)T * QKVN * 4);
  float* h2 = (float*)alloc((size_t)T * H * 4);
  float* gb1 = (float*)alloc((size_t)T * H * 4);    // wo out; later aliased as gS2
  __hip_bfloat16* h1b = (__hip_bfloat16*)alloc((size_t)T * H * 2);  // later aliased as gPs
  __hip_bfloat16* aob = (__hip_bfloat16*)alloc((size_t)T * H * 2);
  __hip_bfloat16* h2b = (__hip_bfloat16*)alloc((size_t)T * H * 2);
  __hip_bfloat16* xgb = (__hip_bfloat16*)alloc((size_t)T * H * 2);
  __hip_bfloat16* gA2 = (__hip_bfloat16*)alloc((size_t)T * 2 * FF * 2);
  __hip_bfloat16* gP = (__hip_bfloat16*)alloc((size_t)T * FF * 2);
  __hip_bfloat16* Qb = (__hip_bfloat16*)alloc((size_t)T * NH * DH * 2);
  __hip_bfloat16* Kb = (__hip_bfloat16*)alloc((size_t)T * NKV * DH * 2);
  __hip_bfloat16* VtG = (__hip_bfloat16*)alloc((size_t)NKV * DH * T * 2);
  __hip_bfloat16* wqkvT = (__hip_bfloat16*)alloc((size_t)H * QKVN * 2);
  __hip_bfloat16* woT = (__hip_bfloat16*)alloc((size_t)H * H * 2);
  __hip_bfloat16* wguT = (__hip_bfloat16*)alloc((size_t)9 * 2 * FF * H * 2);  // slot 8 = shared
  __hip_bfloat16* wdT = (__hip_bfloat16*)alloc((size_t)9 * H * FF * 2);       // slot 8 = shared
  int* counts = (int*)alloc(2 * NE * 4);
  int* cnt2 = counts + NE;
  int* offs = (int*)alloc((NE + 1) * 4);
  int* idx = (int*)alloc(T * 4);
  int* perm = (int*)alloc(T * 4);
  float* gate = (float*)alloc(T * 4);

  // dead-buffer aliases (gb1 dead after fused_add_rms; h1b dead after qkv GEMM)
  __hip_bfloat16* gS2 = (__hip_bfloat16*)gb1;   // T*2FF bf16 = T*H fp32 bytes
  __hip_bfloat16* gPs = h1b;                    // T*FF bf16 <= T*H bf16

  // out is accumulated into by atomic epilogue -> zero it first
  hipMemsetAsync(out, 0, (size_t)T * H * sizeof(float), stream);

  // weight transpose+cast (5 launches)
  tcast9<<<dim3(QKVN / 64, H / 32, 1), 256, 0, stream>>>(wqkv, nullptr, wqkvT, H, QKVN, QKVN, H, 0, 0);
  tcast9<<<dim3(H / 64, H / 32, 1), 256, 0, stream>>>(wo, nullptr, woT, H, H, H, H, 0, 0);
  tcast9<<<dim3(FF / 64, H / 32, 9), 256, 0, stream>>>(w_gate, sh_gate, wguT, H, FF, FF, H,
                                                       (long long)H * FF, (long long)2 * H * FF);
  tcast9<<<dim3(FF / 64, H / 32, 9), 256, 0, stream>>>(w_up, sh_up, wguT + (size_t)FF * H, H, FF, FF, H,
                                                       (long long)H * FF, (long long)2 * H * FF);
  tcast9<<<dim3(H / 64, FF / 32, 9), 256, 0, stream>>>(w_down, sh_down, wdT, FF, H, H, FF,
                                                       (long long)FF * H, (long long)H * FF);

  // 1. h1b = bf16(rmsnorm(hidden) * ln1_w)
  rmsnorm1024<<<T, 256, 0, stream>>>(hidden, ln1_w, h1b);
  // 2. qkv = h1 @ wqkv (fp32)
  gemm_bf16<<<dim3(QKVN / 64, T / 128, 1), 256, 0, stream>>>(h1b, nullptr, wqkvT, qkv, nullptr,
                                                             T, QKVN, H, 0, nullptr, 0, nullptr);
  // 3. RoPE + q/k rmsnorm -> Qb (pre-scaled), Kb
  rope_pack<<<T * (NH + NKV) / 4, 256, 0, stream>>>(qkv, positions, Qb, Kb);
  // 4a. V^T bf16 [NKV*DH][T]
  tcast9<<<dim3(NKV * DH / 64, T / 32, 1), 256, 0, stream>>>(qkv + (NH + NKV) * DH, nullptr, VtG,
                                                             T, NKV * DH, QKVN, T, 0, 0);
  // 4b. attention
  attn_mfma<<<dim3(T / 64, NH), 256, 0, stream>>>(Qb, Kb, VtG, aob);
  // 5. gb1 = ao @ wo (fp32)
  gemm_bf16<<<dim3(H / 64, T / 128, 1), 256, 0, stream>>>(aob, nullptr, woT, gb1, nullptr,
                                                          T, H, H, 0, nullptr, 0, nullptr);
  // 6+7. resid = gb1 + hidden; h2 = rmsnorm(resid)*ln2_w
  fused_add_rms<<<T, 256, 0, stream>>>(gb1, hidden, resid, ln2_w, h2, h2b);
  // 8-10. routing
  zero_counts_kernel<<<1, 64, 0, stream>>>(counts);
  router_kernel<<<T, 64, 0, stream>>>(h2, router_w, idx, gate, counts);
  scan_kernel<<<1, 64, 0, stream>>>(counts, offs);
  // 11. fused assign + gather
  assign_gather<<<T, 256, 0, stream>>>(idx, offs, cnt2, perm, h2, gate, xgb);
  // 12. gate+up: experts (z=0..7 grouped) + shared (z=8, h2b -> gS2)
  gemm_bf16<<<dim3(2 * FF / 64, T / 128, 9), 256, 0, stream>>>(xgb, h2b, wguT, gA2, gS2,
                                                               T, 2 * FF, H, 1, offs,
                                                               (long long)2 * H * FF, nullptr);
  // 13. silu-mul both
  silumul_both<<<(2 * T * FF / 4) / 256, 256, 0, stream>>>(gA2, gS2, gP, gPs, T * FF / 4);
  // 14. down: experts + shared, atomic accumulate directly into out (perm-mapped)
  gemm_bf16<<<dim3(H / 64, T / 128, 9), 256, 0, stream>>>(gP, gPs, wdT, out, out,
                                                          T, H, FF, 2, offs, (long long)FF * H, perm);
}